// Round 7
// baseline (95.683 us; speedup 1.0000x reference)
//
#include <hip/hip_runtime.h>

#define B_ 2
#define N_ 8192
#define K_ 16
#define C_ 64
#define PE_ 32
#define HID_ 16

typedef float f4 __attribute__((ext_vector_type(4)));

// ---------------- Kernel 1: ht[b][n][c] = relu(sum_c' W1[c][c'] * f[b][c'][n] + b1[c])
__global__ __launch_bounds__(256) void k1_conv(
    const float* __restrict__ f, const float* __restrict__ W1,
    const float* __restrict__ b1, float* __restrict__ ht) {
  __shared__ float sf[C_ * 64];  // [c][nl]
  const int t = threadIdx.x;
  const int g0 = blockIdx.x * 64;          // flattened b*N + n base
  const int b = g0 >> 13;
  const int n0 = g0 & (N_ - 1);
  for (int idx = t; idx < C_ * 64; idx += 256) {
    int c = idx >> 6, nl = idx & 63;
    sf[c * 64 + nl] = __builtin_nontemporal_load(&f[(size_t)(b * C_ + c) * N_ + n0 + nl]);
  }
  __syncthreads();
  const int nl = t & 63;
  const int q = t >> 6;  // wave-uniform oc quarter -> W1 via s_load
  float fv[C_];
  #pragma unroll
  for (int c = 0; c < C_; ++c) fv[c] = sf[c * 64 + nl];
  float* op = ht + (size_t)(g0 + nl) * C_ + q * 16;
  #pragma unroll
  for (int o4 = 0; o4 < 4; ++o4) {
    float r[4];
    #pragma unroll
    for (int u = 0; u < 4; ++u) {
      const int oc = q * 16 + o4 * 4 + u;
      float acc = b1[oc];
      #pragma unroll
      for (int c = 0; c < C_; ++c) acc = fmaf(W1[oc * C_ + c], fv[c], acc);
      r[u] = fmaxf(acc, 0.f);
    }
    reinterpret_cast<float4*>(op)[o4] = make_float4(r[0], r[1], r[2], r[3]);
  }
}

// 16x16 in-register transpose within a 16-lane group (masks 1..8 stay in-group).
__device__ __forceinline__ void transpose16(float x[16], int l) {
  #pragma unroll
  for (int m = 1; m < 16; m <<= 1) {
    #pragma unroll
    for (int ii = 0; ii < 16; ++ii) {
      if ((ii & m) == 0) {
        const int jj = ii | m;
        const float send = (l & m) ? x[ii] : x[jj];
        const float recv = __shfl_xor(send, m);
        if (l & m) x[ii] = recv; else x[jj] = recv;
      }
    }
  }
}

// ---------------- Kernel 2+3 fused: per block = 16 points.
// P3 (KDE offsets): register/shuffle-resident — NO runtime-indexed local arrays
// (rule #20: dd-selected pointer in R6 forced pj/pkA/pkB to scratch -> 79 MB
// spill traffic). dd=0 / dd=1 bodies are fully duplicated with named arrays.
__global__ __launch_bounds__(256) void k23(
    const float* __restrict__ p, const float* __restrict__ pe,
    const float* __restrict__ ht, const int* __restrict__ knn,
    const float* __restrict__ Wpe, const float* __restrict__ bpe,
    const float* __restrict__ Wh1, const float* __restrict__ bh1,
    const float* __restrict__ Wh2, const float* __restrict__ bh2,
    float* __restrict__ fout, float* __restrict__ delta) {
  __shared__ __align__(16) char smem[40960];
  float* sfj = (float*)smem;                    // [64][128] swizzled, 32KB
  float* sout = (float*)(smem + 32768);         // [64][20]
  float* sc = (float*)(smem + 32768 + 5120);    // [16][48] coords
  const int t = threadIdx.x;
  const int base = blockIdx.x * 16;             // flattened b*N + n base
  const int b = base >> 13;
  const int n0b = base & (N_ - 1);

  // ================= P3: KDE offset generator =================
  {
    const int g = t >> 4, i = t & 15;
    const int gid = base + g;
    const int idx = knn[(size_t)gid * K_ + i];
    const float* pp = p + (size_t)(b * N_ + idx) * 3;
    const float ci0 = pp[0], ci1 = pp[1], ci2 = pp[2];
    sc[g * 48 + i * 3 + 0] = ci0;
    sc[g * 48 + i * 3 + 1] = ci1;
    sc[g * 48 + i * 3 + 2] = ci2;
    __syncthreads();

    const float4* sq = reinterpret_cast<const float4*>(&sc[g * 48]);
    // lane owns d-pair {2i, 2i+1}. proj trick:
    // relu(Wd.(ci-cj)+bd) = relu((Wd.ci+bd) - Wd.cj)
    float pkA[16], pkB[16];
    {  // ---- channel d = 2i
      const int d = 2 * i;
      const float wx = Wpe[d * 3 + 0], wy = Wpe[d * 3 + 1], wz = Wpe[d * 3 + 2];
      const float wb = bpe[d];
      float pjA[16];
      #pragma unroll
      for (int j4 = 0; j4 < 4; ++j4) {
        const float4 a = sq[j4 * 3 + 0], b4 = sq[j4 * 3 + 1], c4 = sq[j4 * 3 + 2];
        pjA[4 * j4 + 0] = fmaf(wx, a.x, fmaf(wy, a.y, wz * a.z));
        pjA[4 * j4 + 1] = fmaf(wx, a.w, fmaf(wy, b4.x, wz * b4.y));
        pjA[4 * j4 + 2] = fmaf(wx, b4.z, fmaf(wy, b4.w, wz * c4.x));
        pjA[4 * j4 + 3] = fmaf(wx, c4.y, fmaf(wy, c4.z, wz * c4.w));
      }
      #pragma unroll
      for (int ii = 0; ii < 16; ++ii) pkA[ii] = 0.f;
      #pragma unroll
      for (int j = 0; j < 16; ++j) {
        #pragma unroll
        for (int ii = 0; ii < 16; ++ii)
          pkA[ii] += fmaxf(pjA[ii] + wb - pjA[j], 0.f);
      }
    }
    {  // ---- channel d = 2i+1
      const int d = 2 * i + 1;
      const float wx = Wpe[d * 3 + 0], wy = Wpe[d * 3 + 1], wz = Wpe[d * 3 + 2];
      const float wb = bpe[d];
      float pjB[16];
      #pragma unroll
      for (int j4 = 0; j4 < 4; ++j4) {
        const float4 a = sq[j4 * 3 + 0], b4 = sq[j4 * 3 + 1], c4 = sq[j4 * 3 + 2];
        pjB[4 * j4 + 0] = fmaf(wx, a.x, fmaf(wy, a.y, wz * a.z));
        pjB[4 * j4 + 1] = fmaf(wx, a.w, fmaf(wy, b4.x, wz * b4.y));
        pjB[4 * j4 + 2] = fmaf(wx, b4.z, fmaf(wy, b4.w, wz * c4.x));
        pjB[4 * j4 + 3] = fmaf(wx, c4.y, fmaf(wy, c4.z, wz * c4.w));
      }
      #pragma unroll
      for (int ii = 0; ii < 16; ++ii) pkB[ii] = 0.f;
      #pragma unroll
      for (int j = 0; j < 16; ++j) {
        #pragma unroll
        for (int ii = 0; ii < 16; ++ii)
          pkB[ii] += fmaxf(pjB[ii] + wb - pjB[j], 0.f);
      }
    }

    // kde for own point i (coords re-read from LDS, f4 walk)
    const float INV2S = 0.49999975f;
    const float COEF = 0.39894225f;
    float kacc = 0.f;
    #pragma unroll
    for (int j4 = 0; j4 < 4; ++j4) {
      const float4 a = sq[j4 * 3 + 0], b4 = sq[j4 * 3 + 1], c4 = sq[j4 * 3 + 2];
      float dx, dy, dz;
      dx = ci0 - a.x;  dy = ci1 - a.y;  dz = ci2 - a.z;
      kacc += __expf(-(dx * dx + dy * dy + dz * dz) * INV2S);
      dx = ci0 - a.w;  dy = ci1 - b4.x; dz = ci2 - b4.y;
      kacc += __expf(-(dx * dx + dy * dy + dz * dz) * INV2S);
      dx = ci0 - b4.z; dy = ci1 - b4.w; dz = ci2 - c4.x;
      kacc += __expf(-(dx * dx + dy * dy + dz * dz) * INV2S);
      dx = ci0 - c4.y; dy = ci1 - c4.z; dz = ci2 - c4.w;
      kacc += __expf(-(dx * dx + dy * dy + dz * dz) * INV2S);
    }
    const float kde = COEF * kacc;
    float m = kde;
    m = fmaxf(m, __shfl_xor(m, 1));
    m = fmaxf(m, __shfl_xor(m, 2));
    m = fmaxf(m, __shfl_xor(m, 4));
    m = fmaxf(m, __shfl_xor(m, 8));
    const float s = (kde / (m + 1e-6f)) * (1.f / 16.f);

    // 16x32 pek transpose via shuffles: after this, lane i holds point i's
    // pek[2*jj+0] = pkA[jj], pek[2*jj+1] = pkB[jj]
    transpose16(pkA, i);
    transpose16(pkB, i);

    float o0 = bh2[0], o1 = bh2[1], o2 = bh2[2];
    #pragma unroll
    for (int h = 0; h < HID_; ++h) {
      float u = 0.f;
      #pragma unroll
      for (int jj = 0; jj < 16; ++jj) {
        u = fmaf(Wh1[h * PE_ + 2 * jj + 0], pkA[jj], u);
        u = fmaf(Wh1[h * PE_ + 2 * jj + 1], pkB[jj], u);
      }
      const float a = fmaxf(fmaf(s, u, bh1[h]), 0.f);
      o0 = fmaf(Wh2[0 * HID_ + h], a, o0);
      o1 = fmaf(Wh2[1 * HID_ + h], a, o1);
      o2 = fmaf(Wh2[2 * HID_ + h], a, o2);
    }
    float* dp = delta + ((size_t)gid * K_ + i) * 3;
    dp[0] = o0;
    dp[1] = o1;
    dp[2] = o2;
  }

  // ================= P2: fout = max_k(pe + gathered ht) =================
  // (no barrier needed before phase A: sfj/sout disjoint from sc)
  {
    const int lane = t & 63;
    const int w = t >> 6;                  // wave owns k-quarter w
    const int swz = lane & 31;
    const int wele = (lane >> 3) & 3;
    #pragma unroll 1
    for (int si = 0; si < 2; ++si) {
      const int n0 = n0b + si * 8;
      // phase A: gather fj -> swizzled LDS (lane = c, 256B coalesced reads)
      #pragma unroll
      for (int n = 0; n < 8; ++n) {
        const int* kn = knn + (size_t)(b * N_ + n0 + n) * K_ + w * 4;  // uniform
        #pragma unroll
        for (int kk = 0; kk < 4; ++kk) {
          const int id = kn[kk];
          const float hv = ht[(size_t)(b * N_ + id) * C_ + lane];
          sfj[lane * 128 + (((n * 4 + w) ^ swz) << 2) + (kk ^ wele)] = hv;
        }
      }
      __syncthreads();
      // phase B: pe read coalesced (2 c-rows x 512B per wave inst), nontemporal
      const int h = lane >> 5, sl = lane & 31;
      const int n = sl >> 2, j = sl & 3;
      #pragma unroll
      for (int it2 = 0; it2 < 8; ++it2) {
        const int c = it2 * 8 + w * 2 + h;
        const int px = it2 & 3;            // == (c>>3)&3, compile-time
        const f4 pv = __builtin_nontemporal_load(
            reinterpret_cast<const f4*>(pe + ((size_t)(b * C_ + c) * N_ + n0) * K_) + sl);
        const f4 fj = *reinterpret_cast<const f4*>(&sfj[c * 128 + ((sl ^ (c & 31)) << 2)]);
        float v = fmaxf(fmaxf(pv[0] + fj[0 ^ px], pv[1] + fj[1 ^ px]),
                        fmaxf(pv[2] + fj[2 ^ px], pv[3] + fj[3 ^ px]));
        v = fmaxf(v, __shfl_xor(v, 1));
        v = fmaxf(v, __shfl_xor(v, 2));
        if (j == 0) sout[c * 20 + si * 8 + n] = v;
      }
      __syncthreads();
    }
    // fout write: full 64B rows (float4 per thread)
    const int c = t >> 2, q = t & 3;
    const float4 r = *reinterpret_cast<const float4*>(&sout[c * 20 + q * 4]);
    *reinterpret_cast<float4*>(fout + (size_t)(b * C_ + c) * N_ + n0b + q * 4) = r;
  }
}

extern "C" void kernel_launch(void* const* d_in, const int* in_sizes, int n_in,
                              void* d_out, int out_size, void* d_ws, size_t ws_size,
                              hipStream_t stream) {
  // setup_inputs() dict order: p, f, pe, W1, b1, Wpe, bpe, Wh1, bh1, Wh2, bh2, knn_idx
  const float* p   = (const float*)d_in[0];
  const float* f   = (const float*)d_in[1];
  const float* pe  = (const float*)d_in[2];
  const float* W1  = (const float*)d_in[3];
  const float* b1  = (const float*)d_in[4];
  const float* Wpe = (const float*)d_in[5];
  const float* bpe = (const float*)d_in[6];
  const float* Wh1 = (const float*)d_in[7];
  const float* bh1 = (const float*)d_in[8];
  const float* Wh2 = (const float*)d_in[9];
  const float* bh2 = (const float*)d_in[10];
  const int* knn   = (const int*)d_in[11];
  float* fout  = (float*)d_out;                        // [B,C,N]
  float* delta = (float*)d_out + (size_t)B_ * C_ * N_; // [B*N,K,3]
  float* ht = (float*)d_ws;                            // [B,N,C] = 4 MB

  k1_conv<<<(B_ * N_) / 64, 256, 0, stream>>>(f, W1, b1, ht);
  k23<<<(B_ * N_) / 16, 256, 0, stream>>>(p, pe, ht, knn, Wpe, bpe, Wh1, bh1,
                                          Wh2, bh2, fout, delta);
}

// Round 8
// 69.772 us; speedup vs baseline: 1.3714x; 1.3714x over previous
//
#include <hip/hip_runtime.h>

#define B_ 2
#define N_ 8192
#define K_ 16
#define C_ 64
#define PE_ 32
#define HID_ 16

typedef float f4 __attribute__((ext_vector_type(4)));

__device__ __forceinline__ f4 splat4(float x) { f4 r = {x, x, x, x}; return r; }
__device__ __forceinline__ f4 relu4(f4 v) {
  f4 r;
  r[0] = fmaxf(v[0], 0.f); r[1] = fmaxf(v[1], 0.f);
  r[2] = fmaxf(v[2], 0.f); r[3] = fmaxf(v[3], 0.f);
  return r;
}
__device__ __forceinline__ float dot4(float4 w, f4 v) {
  return fmaf(w.x, v[0], fmaf(w.y, v[1], fmaf(w.z, v[2], w.w * v[3])));
}

// pk accumulators for one pe-channel: 4 named f4 (NO arrays -> SROA-safe).
struct PK4 { f4 k0, k1, k2, k3; };

// Compute pk[ii] = sum_j relu((Wd.c_ii + bd) - Wd.c_j) for the 16 points of a
// group, all in named registers. sq = group's coords as float4 triplets.
__device__ __forceinline__ PK4 channel(const float4* __restrict__ sq,
                                       int d, const float* __restrict__ Wpe,
                                       const float* __restrict__ bpe) {
  const float wx = Wpe[d * 3 + 0], wy = Wpe[d * 3 + 1], wz = Wpe[d * 3 + 2];
  const float wb = bpe[d];
  const float4 A0 = sq[0], B0 = sq[1], C0 = sq[2];
  const float4 A1 = sq[3], B1 = sq[4], C1 = sq[5];
  const float4 A2 = sq[6], B2 = sq[7], C2 = sq[8];
  const float4 A3 = sq[9], B3 = sq[10], C3 = sq[11];
  const float p0  = fmaf(wx, A0.x, fmaf(wy, A0.y, wz * A0.z));
  const float p1  = fmaf(wx, A0.w, fmaf(wy, B0.x, wz * B0.y));
  const float p2  = fmaf(wx, B0.z, fmaf(wy, B0.w, wz * C0.x));
  const float p3  = fmaf(wx, C0.y, fmaf(wy, C0.z, wz * C0.w));
  const float p4  = fmaf(wx, A1.x, fmaf(wy, A1.y, wz * A1.z));
  const float p5  = fmaf(wx, A1.w, fmaf(wy, B1.x, wz * B1.y));
  const float p6  = fmaf(wx, B1.z, fmaf(wy, B1.w, wz * C1.x));
  const float p7  = fmaf(wx, C1.y, fmaf(wy, C1.z, wz * C1.w));
  const float p8  = fmaf(wx, A2.x, fmaf(wy, A2.y, wz * A2.z));
  const float p9  = fmaf(wx, A2.w, fmaf(wy, B2.x, wz * B2.y));
  const float p10 = fmaf(wx, B2.z, fmaf(wy, B2.w, wz * C2.x));
  const float p11 = fmaf(wx, C2.y, fmaf(wy, C2.z, wz * C2.w));
  const float p12 = fmaf(wx, A3.x, fmaf(wy, A3.y, wz * A3.z));
  const float p13 = fmaf(wx, A3.w, fmaf(wy, B3.x, wz * B3.y));
  const float p14 = fmaf(wx, B3.z, fmaf(wy, B3.w, wz * C3.x));
  const float p15 = fmaf(wx, C3.y, fmaf(wy, C3.z, wz * C3.w));
  const f4 a0 = {p0 + wb, p1 + wb, p2 + wb, p3 + wb};
  const f4 a1 = {p4 + wb, p5 + wb, p6 + wb, p7 + wb};
  const f4 a2 = {p8 + wb, p9 + wb, p10 + wb, p11 + wb};
  const f4 a3 = {p12 + wb, p13 + wb, p14 + wb, p15 + wb};
  f4 k0 = splat4(0.f), k1 = splat4(0.f), k2 = splat4(0.f), k3 = splat4(0.f);
#define KSTEP(PJ)                                  \
  {                                                \
    const f4 sp = splat4(PJ);                      \
    k0 += relu4(a0 - sp); k1 += relu4(a1 - sp);    \
    k2 += relu4(a2 - sp); k3 += relu4(a3 - sp);    \
  }
  KSTEP(p0) KSTEP(p1) KSTEP(p2) KSTEP(p3) KSTEP(p4) KSTEP(p5) KSTEP(p6)
  KSTEP(p7) KSTEP(p8) KSTEP(p9) KSTEP(p10) KSTEP(p11) KSTEP(p12) KSTEP(p13)
  KSTEP(p14) KSTEP(p15)
#undef KSTEP
  PK4 r; r.k0 = k0; r.k1 = k1; r.k2 = k2; r.k3 = k3;
  return r;
}

// ---------------- Kernel 1: ht[b][n][c] = relu(sum_c' W1[c][c'] * f[b][c'][n] + b1[c])
__global__ __launch_bounds__(256) void k1_conv(
    const float* __restrict__ f, const float* __restrict__ W1,
    const float* __restrict__ b1, float* __restrict__ ht) {
  __shared__ float sf[C_ * 64];  // [c][nl]
  const int t = threadIdx.x;
  const int g0 = blockIdx.x * 64;          // flattened b*N + n base
  const int b = g0 >> 13;
  const int n0 = g0 & (N_ - 1);
  for (int idx = t; idx < C_ * 64; idx += 256) {
    int c = idx >> 6, nl = idx & 63;
    sf[c * 64 + nl] = __builtin_nontemporal_load(&f[(size_t)(b * C_ + c) * N_ + n0 + nl]);
  }
  __syncthreads();
  const int nl = t & 63;
  const int q = t >> 6;  // wave-uniform oc quarter -> W1 via s_load
  float fv[C_];
  #pragma unroll
  for (int c = 0; c < C_; ++c) fv[c] = sf[c * 64 + nl];
  float* op = ht + (size_t)(g0 + nl) * C_ + q * 16;
  #pragma unroll
  for (int o4 = 0; o4 < 4; ++o4) {
    float r[4];
    #pragma unroll
    for (int u = 0; u < 4; ++u) {
      const int oc = q * 16 + o4 * 4 + u;
      float acc = b1[oc];
      #pragma unroll
      for (int c = 0; c < C_; ++c) acc = fmaf(W1[oc * C_ + c], fv[c], acc);
      r[u] = fmaxf(acc, 0.f);
    }
    reinterpret_cast<float4*>(op)[o4] = make_float4(r[0], r[1], r[2], r[3]);
  }
}

// ---------------- Kernel 2+3 fused: per block = 16 points.
// P3: pek via named-register channels + quad-swizzled LDS transpose (spk
// aliases sfj region temporally). P2: max-pool over pe + gathered ht.
__global__ __launch_bounds__(256) void k23(
    const float* __restrict__ p, const float* __restrict__ pe,
    const float* __restrict__ ht, const int* __restrict__ knn,
    const float* __restrict__ Wpe, const float* __restrict__ bpe,
    const float* __restrict__ Wh1, const float* __restrict__ bh1,
    const float* __restrict__ Wh2, const float* __restrict__ bh2,
    float* __restrict__ fout, float* __restrict__ delta) {
  __shared__ __align__(16) char smem[40960];
  float* sfj = (float*)smem;                    // [64][128] swizzled, 32KB (P2)
  float* spk = (float*)smem;                    // [16][16][32] quad-swz, 32KB (P3)
  float* sout = (float*)(smem + 32768);         // [64][20]
  float* sc = (float*)(smem + 32768 + 5120);    // [16][48] coords
  const int t = threadIdx.x;
  const int base = blockIdx.x * 16;             // flattened b*N + n base
  const int b = base >> 13;
  const int n0b = base & (N_ - 1);

  // ================= P3: KDE offset generator =================
  {
    const int g = t >> 4, i = t & 15;
    const int gid = base + g;
    const int idx = knn[(size_t)gid * K_ + i];
    const float* pp = p + (size_t)(b * N_ + idx) * 3;
    const float ci0 = pp[0], ci1 = pp[1], ci2 = pp[2];
    sc[g * 48 + i * 3 + 0] = ci0;
    sc[g * 48 + i * 3 + 1] = ci1;
    sc[g * 48 + i * 3 + 2] = ci2;
    __syncthreads();

    const float4* sq = reinterpret_cast<const float4*>(&sc[g * 48]);
    // lane owns d-pair {2i, 2i+1}; all-pairs relu sums in named registers
    const PK4 cA = channel(sq, 2 * i + 0, Wpe, bpe);
    const PK4 cB = channel(sq, 2 * i + 1, Wpe, bpe);

    // write pek to quad-swizzled LDS: row ii, d=2i..2i+1 -> phys quad (i>>1)^(ii&7)
    {
      const int qw = i >> 1, pos = (2 * i) & 3;
      float* gbase = spk + g * 512;
#define PKW(II, KV)                                                            \
      {                                                                        \
        float2 w2 = make_float2(cA.KV[(II) & 3], cB.KV[(II) & 3]);             \
        *reinterpret_cast<float2*>(                                            \
            &gbase[(II) * 32 + ((qw ^ ((II) & 7)) << 2) + pos]) = w2;          \
      }
      PKW(0, k0) PKW(1, k0) PKW(2, k0) PKW(3, k0)
      PKW(4, k1) PKW(5, k1) PKW(6, k1) PKW(7, k1)
      PKW(8, k2) PKW(9, k2) PKW(10, k2) PKW(11, k2)
      PKW(12, k3) PKW(13, k3) PKW(14, k3) PKW(15, k3)
#undef PKW
    }

    // kde for own point i (coords re-read from LDS, broadcast)
    const float INV2S = 0.49999975f;
    const float COEF = 0.39894225f;
    float kacc = 0.f;
    #pragma unroll
    for (int j4 = 0; j4 < 4; ++j4) {
      const float4 a = sq[j4 * 3 + 0], b4 = sq[j4 * 3 + 1], c4 = sq[j4 * 3 + 2];
      float dx, dy, dz;
      dx = ci0 - a.x;  dy = ci1 - a.y;  dz = ci2 - a.z;
      kacc += __expf(-(dx * dx + dy * dy + dz * dz) * INV2S);
      dx = ci0 - a.w;  dy = ci1 - b4.x; dz = ci2 - b4.y;
      kacc += __expf(-(dx * dx + dy * dy + dz * dz) * INV2S);
      dx = ci0 - b4.z; dy = ci1 - b4.w; dz = ci2 - c4.x;
      kacc += __expf(-(dx * dx + dy * dy + dz * dz) * INV2S);
      dx = ci0 - c4.y; dy = ci1 - c4.z; dz = ci2 - c4.w;
      kacc += __expf(-(dx * dx + dy * dy + dz * dz) * INV2S);
    }
    const float kde = COEF * kacc;
    float m = kde;
    m = fmaxf(m, __shfl_xor(m, 1));
    m = fmaxf(m, __shfl_xor(m, 2));
    m = fmaxf(m, __shfl_xor(m, 4));
    m = fmaxf(m, __shfl_xor(m, 8));
    const float s = (kde / (m + 1e-6f)) * (1.f / 16.f);

    __syncthreads();  // spk writes visible

    // read own pek row (logical quad lq at phys quad lq^(i&7)) into named f4s
    const float* rbase = spk + g * 512 + i * 32;
    const int ix = i & 7;
    const f4 v0 = *reinterpret_cast<const f4*>(&rbase[(0 ^ ix) << 2]);
    const f4 v1 = *reinterpret_cast<const f4*>(&rbase[(1 ^ ix) << 2]);
    const f4 v2 = *reinterpret_cast<const f4*>(&rbase[(2 ^ ix) << 2]);
    const f4 v3 = *reinterpret_cast<const f4*>(&rbase[(3 ^ ix) << 2]);
    const f4 v4 = *reinterpret_cast<const f4*>(&rbase[(4 ^ ix) << 2]);
    const f4 v5 = *reinterpret_cast<const f4*>(&rbase[(5 ^ ix) << 2]);
    const f4 v6 = *reinterpret_cast<const f4*>(&rbase[(6 ^ ix) << 2]);
    const f4 v7 = *reinterpret_cast<const f4*>(&rbase[(7 ^ ix) << 2]);

    float o0 = bh2[0], o1 = bh2[1], o2 = bh2[2];
    #pragma unroll
    for (int h = 0; h < HID_; ++h) {
      const float4* Wr = reinterpret_cast<const float4*>(Wh1 + h * PE_);  // uniform
      float u = dot4(Wr[0], v0) + dot4(Wr[1], v1) + dot4(Wr[2], v2) +
                dot4(Wr[3], v3) + dot4(Wr[4], v4) + dot4(Wr[5], v5) +
                dot4(Wr[6], v6) + dot4(Wr[7], v7);
      const float a = fmaxf(fmaf(s, u, bh1[h]), 0.f);
      o0 = fmaf(Wh2[0 * HID_ + h], a, o0);
      o1 = fmaf(Wh2[1 * HID_ + h], a, o1);
      o2 = fmaf(Wh2[2 * HID_ + h], a, o2);
    }
    float* dp = delta + ((size_t)gid * K_ + i) * 3;
    dp[0] = o0;
    dp[1] = o1;
    dp[2] = o2;
  }

  __syncthreads();  // spk dead; sfj region may now be overwritten

  // ================= P2: fout = max_k(pe + gathered ht) =================
  {
    const int lane = t & 63;
    const int w = t >> 6;                  // wave owns k-quarter w
    const int swz = lane & 31;
    const int wele = (lane >> 3) & 3;
    #pragma unroll 1
    for (int si = 0; si < 2; ++si) {
      const int n0 = n0b + si * 8;
      // phase A: gather fj -> swizzled LDS (lane = c, 256B coalesced reads)
      #pragma unroll
      for (int n = 0; n < 8; ++n) {
        const int* kn = knn + (size_t)(b * N_ + n0 + n) * K_ + w * 4;  // uniform
        #pragma unroll
        for (int kk = 0; kk < 4; ++kk) {
          const int id = kn[kk];
          const float hv = ht[(size_t)(b * N_ + id) * C_ + lane];
          sfj[lane * 128 + (((n * 4 + w) ^ swz) << 2) + (kk ^ wele)] = hv;
        }
      }
      __syncthreads();
      // phase B: pe read coalesced (2 c-rows x 512B per wave inst), nontemporal
      const int h = lane >> 5, sl = lane & 31;
      const int n = sl >> 2, j = sl & 3;
      #pragma unroll
      for (int it2 = 0; it2 < 8; ++it2) {
        const int c = it2 * 8 + w * 2 + h;
        const int px = it2 & 3;            // == (c>>3)&3, compile-time
        const f4 pv = __builtin_nontemporal_load(
            reinterpret_cast<const f4*>(pe + ((size_t)(b * C_ + c) * N_ + n0) * K_) + sl);
        const f4 fj = *reinterpret_cast<const f4*>(&sfj[c * 128 + ((sl ^ (c & 31)) << 2)]);
        float v = fmaxf(fmaxf(pv[0] + fj[0 ^ px], pv[1] + fj[1 ^ px]),
                        fmaxf(pv[2] + fj[2 ^ px], pv[3] + fj[3 ^ px]));
        v = fmaxf(v, __shfl_xor(v, 1));
        v = fmaxf(v, __shfl_xor(v, 2));
        if (j == 0) sout[c * 20 + si * 8 + n] = v;
      }
      __syncthreads();
    }
    // fout write: full 64B rows (float4 per thread)
    const int c = t >> 2, q = t & 3;
    const float4 r = *reinterpret_cast<const float4*>(&sout[c * 20 + q * 4]);
    *reinterpret_cast<float4*>(fout + (size_t)(b * C_ + c) * N_ + n0b + q * 4) = r;
  }
}

extern "C" void kernel_launch(void* const* d_in, const int* in_sizes, int n_in,
                              void* d_out, int out_size, void* d_ws, size_t ws_size,
                              hipStream_t stream) {
  // setup_inputs() dict order: p, f, pe, W1, b1, Wpe, bpe, Wh1, bh1, Wh2, bh2, knn_idx
  const float* p   = (const float*)d_in[0];
  const float* f   = (const float*)d_in[1];
  const float* pe  = (const float*)d_in[2];
  const float* W1  = (const float*)d_in[3];
  const float* b1  = (const float*)d_in[4];
  const float* Wpe = (const float*)d_in[5];
  const float* bpe = (const float*)d_in[6];
  const float* Wh1 = (const float*)d_in[7];
  const float* bh1 = (const float*)d_in[8];
  const float* Wh2 = (const float*)d_in[9];
  const float* bh2 = (const float*)d_in[10];
  const int* knn   = (const int*)d_in[11];
  float* fout  = (float*)d_out;                        // [B,C,N]
  float* delta = (float*)d_out + (size_t)B_ * C_ * N_; // [B*N,K,3]
  float* ht = (float*)d_ws;                            // [B,N,C] = 4 MB

  k1_conv<<<(B_ * N_) / 64, 256, 0, stream>>>(f, W1, b1, ht);
  k23<<<(B_ * N_) / 16, 256, 0, stream>>>(p, pe, ht, knn, Wpe, bpe, Wh1, bh1,
                                          Wh2, bh2, fout, delta);
}